// Round 10
// baseline (160.279 us; speedup 1.0000x reference)
//
#include <hip/hip_runtime.h>

#define BS 2
#define NM 10
#define NA 8400
#define NC 80
#define NBIN 36
#define KTOP 13
#define NRECT (BS*NM*3)   // 60 rects: (bm, level)
#define WDIST_CAP 16384   // max pairs stored in w_dist (actual ~5k)

typedef unsigned long long ull;

// ---------------------------------------------------------------
// Closed-form in-box anchor rectangle for (bm, lv), endpoint-corrected
// with the exact float test the reference uses; membership is exact.
// ---------------------------------------------------------------
__device__ __forceinline__ void rect_one(int bm, int lv,
    const float* __restrict__ gtb, const float* __restrict__ mgt,
    int& x0, int& y0, int& cx, int& cy, int& cnt, int& n, int& base){
  cnt = 0; x0 = 0; y0 = 0; cx = 0; cy = 0; n = 0; base = 0;
  if (mgt[bm] > 0.f){
    float s = (float)(8 << lv);
    n = 640 >> (3 + lv);                     // 80, 40, 20
    base = (lv == 0) ? 0 : ((lv == 1) ? 6400 : 8000);
    float lx = gtb[bm*4+0], ly = gtb[bm*4+1];
    float rx = gtb[bm*4+2], ry = gtb[bm*4+3];
    int a0 = (int)ceilf(lx/s - 0.5f); a0 = min(max(a0, 0), n);
    while (a0 > 0   &&  (((a0-1)+0.5f)*s - lx > 1e-9f)) a0--;
    while (a0 < n   && !(((a0  )+0.5f)*s - lx > 1e-9f)) a0++;
    int a1 = (int)floorf(rx/s - 0.5f); a1 = min(max(a1, -1), n-1);
    while (a1 < n-1 &&  (rx - ((a1+1)+0.5f)*s > 1e-9f)) a1++;
    while (a1 >= 0  && !(rx - ((a1  )+0.5f)*s > 1e-9f)) a1--;
    int b0 = (int)ceilf(ly/s - 0.5f); b0 = min(max(b0, 0), n);
    while (b0 > 0   &&  (((b0-1)+0.5f)*s - ly > 1e-9f)) b0--;
    while (b0 < n   && !(((b0  )+0.5f)*s - ly > 1e-9f)) b0++;
    int b1 = (int)floorf(ry/s - 0.5f); b1 = min(max(b1, -1), n-1);
    while (b1 < n-1 &&  (ry - ((b1+1)+0.5f)*s > 1e-9f)) b1++;
    while (b1 >= 0  && !(ry - ((b1  )+0.5f)*s > 1e-9f)) b1--;
    cx = max(0, a1 - a0 + 1);
    cy = max(0, b1 - b0 + 1);
    cnt = cx * cy;
    x0 = a0; y0 = b0;
  }
}

__device__ __forceinline__ void rect_setup(int tid,
    const float* __restrict__ gtb, const float* __restrict__ mgt,
    int* sx0, int* sy0, int* scx, int* scy, int* scum, int* sn, int* sbase){
  if (tid < NRECT){
    int bm = tid/3, lv = tid - bm*3;
    int x0, y0, cx, cy, cnt, n, base;
    rect_one(bm, lv, gtb, mgt, x0, y0, cx, cy, cnt, n, base);
    sx0[tid] = x0; sy0[tid] = y0; scx[tid] = cx; scy[tid] = cy;
    scum[tid] = cnt; sn[tid] = n; sbase[tid] = base;
  }
  __syncthreads();
  // exclusive prefix over 60 counts via wave0 shfl scan (exact int adds)
  if (tid < 64){
    int c = (tid < NRECT) ? scum[tid] : 0;
    int incl = c;
#pragma unroll
    for (int st = 1; st < 64; st <<= 1){
      int o = __shfl_up(incl, st);
      if (tid >= st) incl += o;
    }
    if (tid < NRECT) scum[tid] = incl - c;           // exclusive
    if (tid == NRECT-1) scum[NRECT] = incl;          // total
  }
  __syncthreads();
}

// binary search: max r with scum[r] <= p
__device__ __forceinline__ int pair_from_p(int p,
    const int* sx0, const int* sy0, const int* scx,
    const int* scum, const int* sn, const int* sbase){
  int lo = 0, hi = NRECT - 1;
  while (lo < hi){ int mid = (lo + hi + 1) >> 1; if (scum[mid] <= p) lo = mid; else hi = mid - 1; }
  int r = lo;
  int idx = p - scum[r];
  int cx = scx[r];
  int yi = idx / cx;
  int xi = idx - yi*cx;
  int a = sbase[r] + (sy0[r] + yi)*sn[r] + (sx0[r] + xi);
  int bm = r/3;
  return bm*NA + a;
}

__device__ __forceinline__ ull shflx_u64(ull v, int off){
  unsigned lo = (unsigned)v, hi = (unsigned)(v >> 32);
  lo = __shfl_xor(lo, off); hi = __shfl_xor(hi, off);
  return ((ull)hi << 32) | lo;
}

// ---------------------------------------------------------------
// k_dist v11: verified bucket-window algorithm (r7/r9 family), TWO pairs
// per 256-thread block in lockstep. Half h = tid>>7 owns pair
// p = 2*blockIdx + h with private LDS state [h]. Five block barriers now
// retire two pairs (per-pair barrier cost halved); the formerly wave0-only
// phases run on waves 0 AND 2 concurrently. All shfl groups (2-lane merge,
// wave prefix, 64-lane fallback butterfly, tail reduce) are wave-internal
// and act-uniform. Selection semantics byte-identical to r6-r9 (verified).
// ---------------------------------------------------------------
__global__ __launch_bounds__(256)
void k_dist(const float* __restrict__ pds, const float* __restrict__ pdb,
            const float* __restrict__ anc, const int* __restrict__ gl,
            const float* __restrict__ gtb, const float* __restrict__ mgt,
            const float* __restrict__ coor,
            float* __restrict__ out, float* __restrict__ wf){
  float* o_labels  = out;
  float* o_bboxes  = o_labels + BS*NA;
  float* o_scores  = o_bboxes + BS*NA*4;
  float* o_maskpos = o_scores + (size_t)BS*NA*NC;
  float* o_gtidx   = o_maskpos + BS*NM*NA;
  float* o_gtdist  = o_gtidx + BS*NA;
  float* o_cent    = o_gtdist + (size_t)BS*NM*NA*NBIN;
  float* o_fg      = o_cent + BS*NM*NA;

  float* w_align = wf + 16;
  float* w_ovl   = w_align + BS*NM*NA;
  float* w_dist  = w_ovl + BS*NM*NA;

  __shared__ int sx0[NRECT], sy0[NRECT], scx[NRECT], scy[NRECT], scum[NRECT+1], sn[NRECT], sbase[NRECT];
  __shared__ float4 s_ad[2][360];            // per half: bucket-sorted (ang, dist, idxf, 0)
  __shared__ int s_cnt[2][NBIN], s_off[2][NBIN+1], s_cur[2][NBIN];
  __shared__ float s_res[2][NBIN];
  __shared__ int s_fbl[2][NBIN];
  __shared__ int s_nfb[2];

  int tid = threadIdx.x;
  int h  = tid >> 7;            // half 0/1 (pair owner)
  int ht = tid & 127;           // id within half
  int lane = ht & 63;           // lane within half's wave
  int wv = ht >> 6;             // wave within half: 0/1 (global waves 0,1 / 2,3)

  rect_setup(tid, gtb, mgt, sx0, sy0, scx, scy, scum, sn, sbase);
  int total = scum[NRECT];

  // ---------------- fused zero/default phase (verified r4-r10) ----------------
  {
    int gtid = blockIdx.x*256 + tid, gsz = gridDim.x*256;
    float4 z4 = make_float4(0.f,0.f,0.f,0.f);
    float4* zs = (float4*)o_scores;
    for (int i = gtid; i < (BS*NA*NC)/4; i += gsz) zs[i] = z4;
    float4* zg = (float4*)o_gtdist;
    for (int i = gtid; i < (BS*NM*NA*NBIN)/4; i += gsz) zg[i] = z4;
    float4* zc = (float4*)o_cent;
    for (int i = gtid; i < (BS*NM*NA)/4; i += gsz) zc[i] = z4;
    float4* zm = (float4*)o_maskpos;
    for (int i = gtid; i < (BS*NM*NA)/4; i += gsz) zm[i] = z4;
    if (gtid < 16) wf[gtid] = 0.f;   // done-counter header
    for (int t = gtid; t < BS*NA; t += gsz){
      int b = t / NA;
      o_gtidx[t] = 0.f;
      o_fg[t] = 0.f;
      int lbl = gl[b*NM]; if (lbl < 0) lbl = 0;
      o_labels[t] = (float)lbl;
      const float* bx = gtb + (b*NM)*4;
      ((float4*)o_bboxes)[t] = make_float4(bx[0], bx[1], bx[2], bx[3]);
    }
    for (int row = gtid; row < BS*NM*NA; row += gsz){
      int bm = row / NA;
      int a  = row - bm*NA;
      int lv = (a < 6400) ? 0 : ((a < 8000) ? 1 : 2);
      int ai = a - ((lv == 0) ? 0 : ((lv == 1) ? 6400 : 8000));
      int r = bm*3 + lv;
      bool inrect = false;
      if (scx[r] > 0 && scy[r] > 0){
        int n = sn[r];
        int y = ai / n, x = ai - y*n;
        inrect = (x >= sx0[r] && x < sx0[r]+scx[r] &&
                  y >= sy0[r] && y < sy0[r]+scy[r]);
      }
      if (!inrect) w_ovl[row] = 0.f;
    }
  }

  if (ht < NBIN) s_cnt[h][ht] = 0;
  if (ht == 0) s_nfb[h] = 0;
  __syncthreads();

  int bin2 = ht >> 1;           // 0..63 (active < 36)
  int slot2 = ht & 1;

  for (int base = blockIdx.x*2; base < total; base += gridDim.x*2){
    int p = base + h;
    bool act = (p < total);
    int t = 0, a = 0, bm = 0, b = 0;
    float ax = 0.f, ay = 0.f;
    const float2* cc2 = (const float2*)coor;
    if (act){
      t = pair_from_p(p, sx0, sy0, scx, scum, sn, sbase);
      a = t % NA; bm = t / NA; b = bm / NM;
      ax = anc[2*a]; ay = anc[2*a+1];
      cc2 = (const float2*)(coor + bm*720);
    }

    // prefetch tail inputs (half-wave 0) — completes under stage/sort
    float pr = 0.f, sc = 0.f;
    if (act && wv == 0){
      if (lane < NBIN) pr = pdb[((size_t)b*NA + a)*NBIN + lane];
      int cls = gl[bm];
      sc = pds[((size_t)b*NA + a)*NC + cls];
    }

    // ---- stage in registers + LDS histogram (3 pts/thread max) ----
    float anR[3], diR[3]; int buR[3];
#pragma unroll
    for (int r = 0; r < 3; r++){
      int i = ht + r*128;
      buR[r] = -1;
      if (act && i < 360){
        float2 cxy = cc2[i];
        float dx = cxy.x - ax;
        float dy = cxy.y - ay;
        diR[r] = sqrtf(dx*dx + dy*dy);
        float an = atan2f(dy, dx) * 57.29577951308232f;
        if (an < 0.f) an += 360.f;
        anR[r] = an;
        int bu = min((int)(an * 0.1f), NBIN-1);
        buR[r] = bu;
        atomicAdd(&s_cnt[h][bu], 1);
      }
    }
    __syncthreads();                                   // bar 1 (2 pairs)

    // ---- prefix (waves 0 and 2, wave-internal shfl) ----
    if (wv == 0){
      int c = (lane < NBIN) ? s_cnt[h][lane] : 0;
      int incl = c;
#pragma unroll
      for (int st = 1; st < 64; st <<= 1){
        int o = __shfl_up(incl, st);
        if (lane >= st) incl += o;
      }
      if (lane < NBIN){ s_off[h][lane+1] = incl; s_cur[h][lane] = incl - c; }
      if (lane == 0) s_off[h][0] = 0;
    }
    __syncthreads();                                   // bar 2

    // ---- scatter from registers (+ reset histogram for next pair) ----
    if (ht < NBIN) s_cnt[h][ht] = 0;
#pragma unroll
    for (int r = 0; r < 3; r++){
      if (buR[r] >= 0){
        int pos = atomicAdd(&s_cur[h][buR[r]], 1);
        s_ad[h][pos] = make_float4(anR[r], diR[r], (float)(ht + r*128), 0.f);
      }
    }
    __syncthreads();                                   // bar 3

#define EVALJ(J, TH) { \
      float4 ad = s_ad[h][J]; \
      unsigned int ixv = (unsigned int)(int)ad.z; \
      float df = fabsf(ad.x - (TH)); \
      df = fminf(df, 360.f - df); \
      ull key = ((ull)__float_as_uint(df) << 32) | ixv; \
      if (key < k3){ \
        k3 = key; d3 = ad.y; \
        if (k3 < k2){ ull tk=k2; k2=k3; k3=tk; float td=d2; d2=d3; d3=td; } \
        if (k2 < k1){ ull tk=k1; k1=k2; k2=tk; float td=d1; d1=d2; d2=td; } \
        if (k1 < k0){ ull tk=k0; k0=k1; k1=tk; float td=d0; d0=d1; d1=td; } \
      } }

    // ---- window scan (2 slots/bin) + in-register 2-lane group merge ----
    if (act && bin2 < NBIN){
      float th = (float)(bin2*10);
      int r0s, r0e, r1s, r1e;
      if (bin2 == 0)      { r0s = s_off[h][35]; r0e = s_off[h][36]; r1s = 0; r1e = s_off[h][2]; }
      else if (bin2 == 35){ r0s = s_off[h][34]; r0e = s_off[h][36]; r1s = 0; r1e = s_off[h][1]; }
      else                { r0s = s_off[h][bin2-1]; r0e = s_off[h][bin2+2]; r1s = 0; r1e = 0; }
      int L0 = r0e - r0s, L = L0 + (r1e - r1s);
      ull k0,k1,k2,k3; float d0,d1,d2,d3;
      k0=k1=k2=k3=~0ull; d0=d1=d2=d3=0.f;
      for (int w = slot2; w < L; w += 2){
        int j = (w < L0) ? (r0s + w) : (r1s + w - L0);
        EVALJ(j, th)
      }
      // merge: 4 rounds of 2-lane group-min (aligned shfl_xor(1)) + pop-front
      float v0m = 0.f, d4v = 0.f, dmax = 0.f;
#pragma unroll
      for (int r = 0; r < 4; r++){
        ull mk = k0; float md = d0;
        ull ok = shflx_u64(mk, 1); float od = __shfl_xor(md, 1);
        if (ok < mk){ mk = ok; md = od; }
        if (r == 0) v0m = __uint_as_float((unsigned)(mk >> 32));
        if (r == 3) d4v = __uint_as_float((unsigned)(mk >> 32));
        dmax = fmaxf(dmax, md);
        if (k0 == mk){ k0=k1; d0=d1; k1=k2; d1=d2; k2=k3; d2=d3; k3=~0ull; d3=0.f; }
      }
      if (slot2 == 0){
        if (!(v0m <= 3.0f)){               // window-min > 3 (or empty/NaN) => masked
          s_res[h][bin2] = 1e-6f;
        } else if (!(d4v <= 9.99f)){       // coverage not guaranteed -> exact fallback
          int fi = atomicAdd(&s_nfb[h], 1);
          s_fbl[h][fi] = bin2;
        } else {
          s_res[h][bin2] = fmaxf(dmax, 1e-6f);
        }
      }
    }
    __syncthreads();                                   // bar 4

    // ---- waves 0/2: rare exact fallback (64-lane butterfly) + tail ----
    if (wv == 0){
      int nfb = act ? s_nfb[h] : 0;
      for (int f = 0; f < nfb; f++){
        int fb = s_fbl[h][f];
        float th = (float)(fb*10);
        ull k0,k1,k2,k3; float d0,d1,d2,d3;
        k0=k1=k2=k3=~0ull; d0=d1=d2=d3=0.f;
        for (int j = lane; j < 360; j += 64){
          EVALJ(j, th)
        }
        ull hk = k0; float hd = d0; int hp = 0;
        float dmax = 0.f;
#pragma unroll
        for (int r = 0; r < 4; r++){
          ull mk = hk; float md = hd;
#pragma unroll
          for (int off = 1; off < 64; off <<= 1){
            ull ok = shflx_u64(mk, off);
            float od = __shfl_xor(md, off);
            if (ok < mk){ mk = ok; md = od; }
          }
          if (hk == mk){
            hp++;
            hk = (hp==1)? k1 : (hp==2)? k2 : (hp==3)? k3 : ~0ull;
            hd = (hp==1)? d1 : (hp==2)? d2 : (hp==3)? d3 : 0.f;
          }
          dmax = fmaxf(dmax, md);
        }
        if (lane == 0) s_res[h][fb] = fmaxf(dmax, 1e-6f);
      }
      if (lane == 0) s_nfb[h] = 0;         // reset for next pair (half-owned)

      // ---- final tail (verified; pr/sc prefetched) ----
      if (act){
        float sum_min = 0.f, sum_max = 0.f;
        if (lane < NBIN){
          float dfin = s_res[h][lane];
          if (p < WDIST_CAP) w_dist[(size_t)p*NBIN + lane] = dfin;
          sum_max = fmaxf(dfin, pr);
          sum_min = fmaxf(fminf(dfin, pr), 1e-6f);
        }
        for (int off = 32; off > 0; off >>= 1){
          sum_min += __shfl_down(sum_min, off);
          sum_max += __shfl_down(sum_max, off);
        }
        if (lane == 0){
          float ov = sum_min / sum_max;
          w_align[t] = sc * ov * ov * ov;
          w_ovl[t]   = ov;
        }
      }
    }
#undef EVALJ
    __syncthreads();                                   // bar 5 / loop barrier
  }
}

// ---------------------------------------------------------------
// k_tail (verified r5-r10): 20 blocks x 256 threads, plain launch.
// Phase T per block; last block (atomic counter) runs F+Z per-thread.
// ---------------------------------------------------------------
__global__ __launch_bounds__(256)
void k_tail(const float* __restrict__ gtb, const float* __restrict__ mgt,
            const float* __restrict__ w_align, const float* __restrict__ w_ovl,
            const float* __restrict__ w_dist, const int* __restrict__ gl,
            float* __restrict__ o_labels, float* __restrict__ o_bboxes,
            float* __restrict__ o_maskpos, float* __restrict__ o_gtidx,
            float* __restrict__ o_fg,
            float* __restrict__ o_gtdist, float* __restrict__ o_cent,
            float* __restrict__ o_scores,
            int* __restrict__ w_sel, int* __restrict__ done){
  __shared__ int sx0[NRECT], sy0[NRECT], scx[NRECT], scy[NRECT], scum[NRECT+1], sn[NRECT], sbase[NRECT];
  __shared__ float sv[256*KTOP];
  __shared__ int   si[256*KTOP];
  __shared__ float wv4[4];
  __shared__ int   wi4[4];
  __shared__ int   sel[BS*NM*KTOP];
  __shared__ unsigned paB[BS*NM], poB[BS*NM];
  __shared__ int fcnt;
  __shared__ int   fT[BS*NM*KTOP];
  __shared__ int   fA[BS*NM*KTOP];
  __shared__ int   fL[BS*NM*KTOP];
  __shared__ float fV[BS*NM*KTOP];
  __shared__ int sLast;

  int tid = threadIdx.x;
  int lane = tid & 63, wave = tid >> 6;

  rect_setup(tid, gtb, mgt, sx0, sy0, scx, scy, scum, sn, sbase);

  int bm = blockIdx.x;
  {
    const float* al = w_align + (size_t)bm*NA;
    int pbase = scum[bm*3], pm1 = scum[bm*3+1], pm2 = scum[bm*3+2], pend = scum[bm*3+3];

    float v[KTOP]; int ix[KTOP];
#pragma unroll
    for (int j = 0; j < KTOP; j++){ v[j] = -1.f; ix[j] = 0x7fffffff; }
    for (int p = pbase + tid; p < pend; p += 256){
      int r = bm*3 + ((p >= pm1) + (p >= pm2));
      int idx = p - scum[r];
      int cx = scx[r];
      int yi = idx / cx;
      int xi = idx - yi*cx;
      int a = sbase[r] + (sy0[r] + yi)*sn[r] + (sx0[r] + xi);
      float x = al[a];
      if (x > v[KTOP-1]){
        v[KTOP-1] = x; ix[KTOP-1] = a;
#pragma unroll
        for (int j = KTOP-1; j > 0; j--){
          if (v[j] > v[j-1]){
            float tv = v[j-1]; v[j-1] = v[j]; v[j] = tv;
            int   ti = ix[j-1]; ix[j-1] = ix[j]; ix[j] = ti;
          }
        }
      }
    }
#pragma unroll
    for (int j = 0; j < KTOP; j++){ sv[tid*KTOP+j] = v[j]; si[tid*KTOP+j] = ix[j]; }

    int head = 0;
    for (int r = 0; r < KTOP; r++){
      float cv = sv[tid*KTOP + head];
      int   ci = si[tid*KTOP + head];
      float rv = cv; int ri = ci;
      for (int off = 32; off > 0; off >>= 1){
        float ov = __shfl_down(rv, off);
        int   oi = __shfl_down(ri, off);
        if (ov > rv || (ov == rv && oi < ri)){ rv = ov; ri = oi; }
      }
      if (lane == 0){ wv4[wave] = rv; wi4[wave] = ri; }
      __syncthreads();
      float Wv = wv4[0]; int Wi = wi4[0];
#pragma unroll
      for (int w = 1; w < 4; w++){
        float ov = wv4[w]; int oi = wi4[w];
        if (ov > Wv || (ov == Wv && oi < Wi)){ Wv = ov; Wi = oi; }
      }
      if (ci == Wi && head < KTOP-1) head++;
      if (tid == 0)
        __hip_atomic_store(&w_sel[bm*KTOP + r], (Wv > 0.f) ? Wi : -1,
                           __ATOMIC_RELAXED, __HIP_MEMORY_SCOPE_AGENT);
      __syncthreads();
    }
  }

  if (tid == 0){
    __threadfence();
    int old = __hip_atomic_fetch_add(done, 1, __ATOMIC_ACQ_REL, __HIP_MEMORY_SCOPE_AGENT);
    sLast = (old == BS*NM - 1) ? 1 : 0;
  }
  __syncthreads();
  if (!sLast) return;

  for (int s = tid; s < BS*NM*KTOP; s += 256)
    sel[s] = __hip_atomic_load(&w_sel[s], __ATOMIC_RELAXED, __HIP_MEMORY_SCOPE_AGENT);
  if (tid < BS*NM){ paB[tid] = 0u; poB[tid] = 0u; }
  if (tid == 0) fcnt = 0;
  __syncthreads();

  for (int s = tid; s < BS*NM*KTOP; s += 256){
    int a = sel[s];
    if (a >= 0){
      int sbm = s / KTOP;
      int b   = sbm / NM;
      int s0 = b*NM*KTOP;
      int cnt = 0, minS = 1 << 30;
      for (int s2 = s0; s2 < s0 + NM*KTOP; s2++){
        if (sel[s2] == a){ cnt++; if (s2 < minS) minS = s2; }
      }
      if (s == minS){
        int bi = sbm - b*NM;
        if (cnt > 1){
          float bv = -1.f; bi = 0;
#pragma unroll
          for (int mm = 0; mm < NM; mm++){
            float vv = w_ovl[((size_t)(b*NM+mm))*NA + a];
            if (vv > bv){ bv = vv; bi = mm; }
          }
        }
        int bmw = b*NM + bi;
        int ta  = b*NA + a;
        o_maskpos[(size_t)bmw*NA + a] = 1.f;
        o_gtidx[ta] = (float)bi;
        o_fg[ta] = 1.f;
        int lbl = gl[bmw]; if (lbl < 0) lbl = 0;
        o_labels[ta] = (float)lbl;
        const float* bx = gtb + bmw*4;
        ((float4*)o_bboxes)[ta] = make_float4(bx[0], bx[1], bx[2], bx[3]);
        float av  = w_align[(size_t)bmw*NA + a];
        float ovv = w_ovl[(size_t)bmw*NA + a];
        atomicMax(&paB[bmw], __float_as_uint(av));
        atomicMax(&poB[bmw], __float_as_uint(ovv));
        int j = atomicAdd(&fcnt, 1);
        fT[j] = bmw*NA + a; fA[j] = ta; fL[j] = lbl; fV[j] = av;
      }
    }
  }
  __syncthreads();

  int nf = fcnt;
  for (int j = tid; j < nf; j += 256){
    int tf = fT[j];
    int a = tf % NA; int bmw = tf / NA;
    int lv = (a < 6400) ? 0 : ((a < 8000) ? 1 : 2);
    int ai = a - ((lv == 0) ? 0 : ((lv == 1) ? 6400 : 8000));
    int r = bmw*3 + lv;
    int n = sn[r];
    int y = ai / n, x = ai - y*n;
    int p = scum[r] + (y - sy0[r])*scx[r] + (x - sx0[r]);
    const float4* src = (const float4*)(w_dist + (size_t)p*NBIN);
    float4* dst = (float4*)(o_gtdist + (size_t)tf*NBIN);
    float vmin = 1e30f, vmax = 0.f;
#pragma unroll
    for (int q = 0; q < 9; q++){
      float4 v4 = src[q];
      dst[q] = v4;
      vmin = fminf(vmin, fminf(fminf(v4.x, v4.y), fminf(v4.z, v4.w)));
      vmax = fmaxf(vmax, fmaxf(fmaxf(v4.x, v4.y), fmaxf(v4.z, v4.w)));
    }
    o_cent[tf] = sqrtf(vmin / vmax);
    float paf = __uint_as_float(paB[bmw]);
    float pof = __uint_as_float(poB[bmw]);
    o_scores[(size_t)fA[j]*NC + fL[j]] = fV[j] * pof / (paf + 1e-9f);
  }
}

extern "C" void kernel_launch(void* const* d_in, const int* in_sizes, int n_in,
                              void* d_out, int out_size, void* d_ws, size_t ws_size,
                              hipStream_t stream){
  const float* pds  = (const float*)d_in[0]; // (2,8400,80)
  const float* pdb  = (const float*)d_in[1]; // (2,8400,36)
  const float* anc  = (const float*)d_in[2]; // (8400,2)
  const int*   gl   = (const int*)  d_in[3]; // (2,10,1)
  const float* gtb  = (const float*)d_in[4]; // (2,10,4)
  const float* mgt  = (const float*)d_in[5]; // (2,10,1)
  const float* coor = (const float*)d_in[6]; // (2,10,720)

  float* out = (float*)d_out;
  float* o_labels  = out;                                 // 16800
  float* o_bboxes  = o_labels + BS*NA;                    // 67200
  float* o_scores  = o_bboxes + BS*NA*4;                  // 1344000
  float* o_maskpos = o_scores + (size_t)BS*NA*NC;         // 168000
  float* o_gtidx   = o_maskpos + BS*NM*NA;                // 16800
  float* o_gtdist  = o_gtidx + BS*NA;                     // 6048000
  float* o_cent    = o_gtdist + (size_t)BS*NM*NA*NBIN;    // 168000
  float* o_fg      = o_cent + BS*NM*NA;                   // 16800

  float* wf      = (float*)d_ws;
  int*   done    = (int*)d_ws;                            // wf[0], zeroed by k_dist
  float* w_align = wf + 16;
  float* w_ovl   = w_align + BS*NM*NA;
  float* w_dist  = w_ovl + BS*NM*NA;                      // WDIST_CAP*36 floats
  int*   w_sel   = (int*)(w_dist + (size_t)WDIST_CAP*NBIN);

  k_dist<<<2400, 256, 0, stream>>>(pds, pdb, anc, gl, gtb, mgt, coor, out, wf);
  k_tail<<<BS*NM, 256, 0, stream>>>(gtb, mgt, w_align, w_ovl, w_dist, gl,
                                    o_labels, o_bboxes, o_maskpos, o_gtidx, o_fg,
                                    o_gtdist, o_cent, o_scores, w_sel, done);
}

// Round 11
// 153.722 us; speedup vs baseline: 1.0427x; 1.0427x over previous
//
#include <hip/hip_runtime.h>

#define BS 2
#define NM 10
#define NA 8400
#define NC 80
#define NBIN 36
#define KTOP 13
#define NRECT (BS*NM*3)   // 60 rects: (bm, level)
#define WDIST_CAP 16384   // max pairs stored in w_dist (actual ~5k)

typedef unsigned long long ull;

// ---------------------------------------------------------------
// Closed-form in-box anchor rectangle for (bm, lv), endpoint-corrected
// with the exact float test the reference uses; membership is exact.
// ---------------------------------------------------------------
__device__ __forceinline__ void rect_one(int bm, int lv,
    const float* __restrict__ gtb, const float* __restrict__ mgt,
    int& x0, int& y0, int& cx, int& cy, int& cnt, int& n, int& base){
  cnt = 0; x0 = 0; y0 = 0; cx = 0; cy = 0; n = 0; base = 0;
  if (mgt[bm] > 0.f){
    float s = (float)(8 << lv);
    n = 640 >> (3 + lv);                     // 80, 40, 20
    base = (lv == 0) ? 0 : ((lv == 1) ? 6400 : 8000);
    float lx = gtb[bm*4+0], ly = gtb[bm*4+1];
    float rx = gtb[bm*4+2], ry = gtb[bm*4+3];
    int a0 = (int)ceilf(lx/s - 0.5f); a0 = min(max(a0, 0), n);
    while (a0 > 0   &&  (((a0-1)+0.5f)*s - lx > 1e-9f)) a0--;
    while (a0 < n   && !(((a0  )+0.5f)*s - lx > 1e-9f)) a0++;
    int a1 = (int)floorf(rx/s - 0.5f); a1 = min(max(a1, -1), n-1);
    while (a1 < n-1 &&  (rx - ((a1+1)+0.5f)*s > 1e-9f)) a1++;
    while (a1 >= 0  && !(rx - ((a1  )+0.5f)*s > 1e-9f)) a1--;
    int b0 = (int)ceilf(ly/s - 0.5f); b0 = min(max(b0, 0), n);
    while (b0 > 0   &&  (((b0-1)+0.5f)*s - ly > 1e-9f)) b0--;
    while (b0 < n   && !(((b0  )+0.5f)*s - ly > 1e-9f)) b0++;
    int b1 = (int)floorf(ry/s - 0.5f); b1 = min(max(b1, -1), n-1);
    while (b1 < n-1 &&  (ry - ((b1+1)+0.5f)*s > 1e-9f)) b1++;
    while (b1 >= 0  && !(ry - ((b1  )+0.5f)*s > 1e-9f)) b1--;
    cx = max(0, a1 - a0 + 1);
    cy = max(0, b1 - b0 + 1);
    cnt = cx * cy;
    x0 = a0; y0 = b0;
  }
}

__device__ __forceinline__ void rect_setup(int tid,
    const float* __restrict__ gtb, const float* __restrict__ mgt,
    int* sx0, int* sy0, int* scx, int* scy, int* scum, int* sn, int* sbase){
  if (tid < NRECT){
    int bm = tid/3, lv = tid - bm*3;
    int x0, y0, cx, cy, cnt, n, base;
    rect_one(bm, lv, gtb, mgt, x0, y0, cx, cy, cnt, n, base);
    sx0[tid] = x0; sy0[tid] = y0; scx[tid] = cx; scy[tid] = cy;
    scum[tid] = cnt; sn[tid] = n; sbase[tid] = base;
  }
  __syncthreads();
  // exclusive prefix over 60 counts via wave0 shfl scan (exact int adds)
  if (tid < 64){
    int c = (tid < NRECT) ? scum[tid] : 0;
    int incl = c;
#pragma unroll
    for (int st = 1; st < 64; st <<= 1){
      int o = __shfl_up(incl, st);
      if (tid >= st) incl += o;
    }
    if (tid < NRECT) scum[tid] = incl - c;           // exclusive
    if (tid == NRECT-1) scum[NRECT] = incl;          // total
  }
  __syncthreads();
}

// binary search: max r with scum[r] <= p
__device__ __forceinline__ int pair_from_p(int p,
    const int* sx0, const int* sy0, const int* scx,
    const int* scum, const int* sn, const int* sbase){
  int lo = 0, hi = NRECT - 1;
  while (lo < hi){ int mid = (lo + hi + 1) >> 1; if (scum[mid] <= p) lo = mid; else hi = mid - 1; }
  int r = lo;
  int idx = p - scum[r];
  int cx = scx[r];
  int yi = idx / cx;
  int xi = idx - yi*cx;
  int a = sbase[r] + (sy0[r] + yi)*sn[r] + (sx0[r] + xi);
  int bm = r/3;
  return bm*NA + a;
}

__device__ __forceinline__ ull shflx_u64(ull v, int off){
  unsigned lo = (unsigned)v, hi = (unsigned)(v >> 32);
  lo = __shfl_xor(lo, off); hi = __shfl_xor(hi, off);
  return ((ull)hi << 32) | lo;
}

// ---------------------------------------------------------------
// k_dist v8 (champion, r7): bucket-window top-4 with register-resident
// merge. Per pair: stage 360 (ang,dist,bucket) in REGISTERS + LDS
// histogram -> wave0 shfl prefix -> scatter (regs -> bucket-sorted s_ad)
// -> (bin = tid>>2, slot = tid&3) window scan, sorted top-4 in regs,
// 4-way merge via aligned shfl_xor group butterfly -> rare exact
// wave-parallel fallback -> wave0 tail with prefetched pdb/gl/pds.
// Selection key u64 (diff|idx): order-independent, lax.top_k-exact.
// ---------------------------------------------------------------
__global__ __launch_bounds__(256)
void k_dist(const float* __restrict__ pds, const float* __restrict__ pdb,
            const float* __restrict__ anc, const int* __restrict__ gl,
            const float* __restrict__ gtb, const float* __restrict__ mgt,
            const float* __restrict__ coor,
            float* __restrict__ out, float* __restrict__ wf){
  float* o_labels  = out;
  float* o_bboxes  = o_labels + BS*NA;
  float* o_scores  = o_bboxes + BS*NA*4;
  float* o_maskpos = o_scores + (size_t)BS*NA*NC;
  float* o_gtidx   = o_maskpos + BS*NM*NA;
  float* o_gtdist  = o_gtidx + BS*NA;
  float* o_cent    = o_gtdist + (size_t)BS*NM*NA*NBIN;
  float* o_fg      = o_cent + BS*NM*NA;

  float* w_align = wf + 16;
  float* w_ovl   = w_align + BS*NM*NA;
  float* w_dist  = w_ovl + BS*NM*NA;

  __shared__ int sx0[NRECT], sy0[NRECT], scx[NRECT], scy[NRECT], scum[NRECT+1], sn[NRECT], sbase[NRECT];
  __shared__ float2 s_ad[360];            // bucket-sorted (ang, dist)
  __shared__ unsigned short s_ix[360];    // original point index
  __shared__ int s_cnt[NBIN], s_off[NBIN+1], s_cur[NBIN];
  __shared__ float s_res[NBIN];
  __shared__ int s_fbl[NBIN];
  __shared__ int s_nfb;

  int tid = threadIdx.x;
  int lane = tid & 63, wave = tid >> 6;

  rect_setup(tid, gtb, mgt, sx0, sy0, scx, scy, scum, sn, sbase);
  int total = scum[NRECT];

  // ---------------- fused zero/default phase (verified r4-r10) ----------------
  {
    int gtid = blockIdx.x*256 + tid, gsz = gridDim.x*256;
    float4 z4 = make_float4(0.f,0.f,0.f,0.f);
    float4* zs = (float4*)o_scores;
    for (int i = gtid; i < (BS*NA*NC)/4; i += gsz) zs[i] = z4;
    float4* zg = (float4*)o_gtdist;
    for (int i = gtid; i < (BS*NM*NA*NBIN)/4; i += gsz) zg[i] = z4;
    float4* zc = (float4*)o_cent;
    for (int i = gtid; i < (BS*NM*NA)/4; i += gsz) zc[i] = z4;
    float4* zm = (float4*)o_maskpos;
    for (int i = gtid; i < (BS*NM*NA)/4; i += gsz) zm[i] = z4;
    if (gtid < 16) wf[gtid] = 0.f;   // done-counter header
    for (int t = gtid; t < BS*NA; t += gsz){
      int b = t / NA;
      o_gtidx[t] = 0.f;
      o_fg[t] = 0.f;
      int lbl = gl[b*NM]; if (lbl < 0) lbl = 0;
      o_labels[t] = (float)lbl;
      const float* bx = gtb + (b*NM)*4;
      ((float4*)o_bboxes)[t] = make_float4(bx[0], bx[1], bx[2], bx[3]);
    }
    for (int row = gtid; row < BS*NM*NA; row += gsz){
      int bm = row / NA;
      int a  = row - bm*NA;
      int lv = (a < 6400) ? 0 : ((a < 8000) ? 1 : 2);
      int ai = a - ((lv == 0) ? 0 : ((lv == 1) ? 6400 : 8000));
      int r = bm*3 + lv;
      bool inrect = false;
      if (scx[r] > 0 && scy[r] > 0){
        int n = sn[r];
        int y = ai / n, x = ai - y*n;
        inrect = (x >= sx0[r] && x < sx0[r]+scx[r] &&
                  y >= sy0[r] && y < sy0[r]+scy[r]);
      }
      if (!inrect) w_ovl[row] = 0.f;
    }
  }

  if (tid < NBIN) s_cnt[tid] = 0;
  if (tid == 0) s_nfb = 0;
  __syncthreads();

  int bin4 = tid >> 2;          // 0..63 (active < 36)
  int slot4 = tid & 3;

  for (int p = blockIdx.x; p < total; p += gridDim.x){
    int t = pair_from_p(p, sx0, sy0, scx, scum, sn, sbase);
    int a = t % NA; int bm = t / NA; int b = bm / NM;
    float ax = anc[2*a], ay = anc[2*a+1];
    const float2* cc2 = (const float2*)(coor + bm*720);

    // prefetch tail inputs (wave0) — completes under stage/sort
    float pr = 0.f, sc = 0.f;
    if (wave == 0){
      if (lane < NBIN) pr = pdb[((size_t)b*NA + a)*NBIN + lane];
      int cls = gl[bm];
      sc = pds[((size_t)b*NA + a)*NC + cls];
    }

    // ---- stage in registers + LDS histogram ----
    float an0, di0, an1 = 0.f, di1 = 0.f;
    int bu0, bu1 = -1;
    {
      float2 cxy = cc2[tid];
      float dx = cxy.x - ax;
      float dy = cxy.y - ay;
      di0 = sqrtf(dx*dx + dy*dy);
      an0 = atan2f(dy, dx) * 57.29577951308232f;
      if (an0 < 0.f) an0 += 360.f;
      bu0 = min((int)(an0 * 0.1f), NBIN-1);
      atomicAdd(&s_cnt[bu0], 1);
    }
    if (tid < 104){
      int i = tid + 256;
      float2 cxy = cc2[i];
      float dx = cxy.x - ax;
      float dy = cxy.y - ay;
      di1 = sqrtf(dx*dx + dy*dy);
      an1 = atan2f(dy, dx) * 57.29577951308232f;
      if (an1 < 0.f) an1 += 360.f;
      bu1 = min((int)(an1 * 0.1f), NBIN-1);
      atomicAdd(&s_cnt[bu1], 1);
    }
    __syncthreads();                                   // bar 1

    // ---- prefix (wave0 shfl) ----
    if (wave == 0){
      int c = (lane < NBIN) ? s_cnt[lane] : 0;
      int incl = c;
#pragma unroll
      for (int st = 1; st < 64; st <<= 1){
        int o = __shfl_up(incl, st);
        if (lane >= st) incl += o;
      }
      if (lane < NBIN){ s_off[lane+1] = incl; s_cur[lane] = incl - c; }
      if (lane == 0) s_off[0] = 0;
    }
    __syncthreads();                                   // bar 2

    // ---- scatter from registers (+ reset counters for next pair) ----
    if (tid < NBIN) s_cnt[tid] = 0;
    if (tid == 64) s_nfb = 0;
    {
      int pos = atomicAdd(&s_cur[bu0], 1);
      s_ad[pos] = make_float2(an0, di0);
      s_ix[pos] = (unsigned short)tid;
    }
    if (bu1 >= 0){
      int pos = atomicAdd(&s_cur[bu1], 1);
      s_ad[pos] = make_float2(an1, di1);
      s_ix[pos] = (unsigned short)(tid + 256);
    }
    __syncthreads();                                   // bar 3

#define EVALJ(J, TH) { \
      float2 ad = s_ad[J]; \
      unsigned int ixv = s_ix[J]; \
      float df = fabsf(ad.x - (TH)); \
      df = fminf(df, 360.f - df); \
      ull key = ((ull)__float_as_uint(df) << 32) | ixv; \
      if (key < k3){ \
        k3 = key; d3 = ad.y; \
        if (k3 < k2){ ull tk=k2; k2=k3; k3=tk; float td=d2; d2=d3; d3=td; } \
        if (k2 < k1){ ull tk=k1; k1=k2; k2=tk; float td=d1; d1=d2; d2=td; } \
        if (k1 < k0){ ull tk=k0; k0=k1; k1=tk; float td=d0; d0=d1; d1=td; } \
      } }

    // ---- window scan + in-register 4-way group merge ----
    if (bin4 < NBIN){
      float th = (float)(bin4*10);
      int r0s, r0e, r1s, r1e;
      if (bin4 == 0)      { r0s = s_off[35]; r0e = s_off[36]; r1s = 0; r1e = s_off[2]; }
      else if (bin4 == 35){ r0s = s_off[34]; r0e = s_off[36]; r1s = 0; r1e = s_off[1]; }
      else                { r0s = s_off[bin4-1]; r0e = s_off[bin4+2]; r1s = 0; r1e = 0; }
      int L0 = r0e - r0s, L = L0 + (r1e - r1s);
      ull k0,k1,k2,k3; float d0,d1,d2,d3;
      k0=k1=k2=k3=~0ull; d0=d1=d2=d3=0.f;
      for (int w = slot4; w < L; w += 4){
        int j = (w < L0) ? (r0s + w) : (r1s + w - L0);
        EVALJ(j, th)
      }
      // merge: 4 rounds of group-min butterfly (lanes 4-aligned) + pop-front
      float v0m = 0.f, d4v = 0.f, dmax = 0.f;
#pragma unroll
      for (int r = 0; r < 4; r++){
        ull mk = k0; float md = d0;
        ull ok = shflx_u64(mk, 1); float od = __shfl_xor(md, 1);
        if (ok < mk){ mk = ok; md = od; }
        ok = shflx_u64(mk, 2); od = __shfl_xor(md, 2);
        if (ok < mk){ mk = ok; md = od; }
        if (r == 0) v0m = __uint_as_float((unsigned)(mk >> 32));
        if (r == 3) d4v = __uint_as_float((unsigned)(mk >> 32));
        dmax = fmaxf(dmax, md);
        if (k0 == mk){ k0=k1; d0=d1; k1=k2; d1=d2; k2=k3; d2=d3; k3=~0ull; d3=0.f; }
      }
      if (slot4 == 0){
        if (!(v0m <= 3.0f)){               // window-min > 3 (or empty/NaN) => masked
          s_res[bin4] = 1e-6f;
        } else if (!(d4v <= 9.99f)){       // coverage not guaranteed -> exact fallback
          int fi = atomicAdd(&s_nfb, 1);
          s_fbl[fi] = bin4;
        } else {
          s_res[bin4] = fmaxf(dmax, 1e-6f);
        }
      }
    }
    __syncthreads();                                   // bar 4

    // ---- rare exact fallback: full-360 rescan, one wave per flagged bin ----
    int nfb = s_nfb;
    if (nfb > 0){
      for (int f = wave; f < nfb; f += 4){
        int fb = s_fbl[f];
        float th = (float)(fb*10);
        ull k0,k1,k2,k3; float d0,d1,d2,d3;
        k0=k1=k2=k3=~0ull; d0=d1=d2=d3=0.f;
        for (int j = lane; j < 360; j += 64){
          EVALJ(j, th)
        }
        ull hk = k0; float hd = d0; int hp = 0;
        float dmax = 0.f;
#pragma unroll
        for (int r = 0; r < 4; r++){
          ull mk = hk; float md = hd;
#pragma unroll
          for (int off = 1; off < 64; off <<= 1){
            ull ok = shflx_u64(mk, off);
            float od = __shfl_xor(md, off);
            if (ok < mk){ mk = ok; md = od; }
          }
          if (hk == mk){
            hp++;
            hk = (hp==1)? k1 : (hp==2)? k2 : (hp==3)? k3 : ~0ull;
            hd = (hp==1)? d1 : (hp==2)? d2 : (hp==3)? d3 : 0.f;
          }
          dmax = fmaxf(dmax, md);
        }
        if (lane == 0) s_res[fb] = fmaxf(dmax, 1e-6f);
      }
      __syncthreads();                                 // bar 5 (uniform-conditional)
    }
#undef EVALJ

    // ---- final tail (verified; pr/sc prefetched) ----
    if (wave == 0){
      float sum_min = 0.f, sum_max = 0.f;
      if (lane < NBIN){
        float dfin = s_res[lane];
        if (p < WDIST_CAP) w_dist[(size_t)p*NBIN + lane] = dfin;
        sum_max = fmaxf(dfin, pr);
        sum_min = fmaxf(fminf(dfin, pr), 1e-6f);
      }
      for (int off = 32; off > 0; off >>= 1){
        sum_min += __shfl_down(sum_min, off);
        sum_max += __shfl_down(sum_max, off);
      }
      if (lane == 0){
        float ov = sum_min / sum_max;
        w_align[t] = sc * ov * ov * ov;
        w_ovl[t]   = ov;
      }
    }
    __syncthreads();                                   // loop barrier (orders s_res reads vs next writes)
  }
}

// ---------------------------------------------------------------
// k_tail (verified r5-r10): 20 blocks x 256 threads, plain launch.
// Phase T per block; last block (atomic counter) runs F+Z per-thread.
// ---------------------------------------------------------------
__global__ __launch_bounds__(256)
void k_tail(const float* __restrict__ gtb, const float* __restrict__ mgt,
            const float* __restrict__ w_align, const float* __restrict__ w_ovl,
            const float* __restrict__ w_dist, const int* __restrict__ gl,
            float* __restrict__ o_labels, float* __restrict__ o_bboxes,
            float* __restrict__ o_maskpos, float* __restrict__ o_gtidx,
            float* __restrict__ o_fg,
            float* __restrict__ o_gtdist, float* __restrict__ o_cent,
            float* __restrict__ o_scores,
            int* __restrict__ w_sel, int* __restrict__ done){
  __shared__ int sx0[NRECT], sy0[NRECT], scx[NRECT], scy[NRECT], scum[NRECT+1], sn[NRECT], sbase[NRECT];
  __shared__ float sv[256*KTOP];
  __shared__ int   si[256*KTOP];
  __shared__ float wv4[4];
  __shared__ int   wi4[4];
  __shared__ int   sel[BS*NM*KTOP];
  __shared__ unsigned paB[BS*NM], poB[BS*NM];
  __shared__ int fcnt;
  __shared__ int   fT[BS*NM*KTOP];
  __shared__ int   fA[BS*NM*KTOP];
  __shared__ int   fL[BS*NM*KTOP];
  __shared__ float fV[BS*NM*KTOP];
  __shared__ int sLast;

  int tid = threadIdx.x;
  int lane = tid & 63, wave = tid >> 6;

  rect_setup(tid, gtb, mgt, sx0, sy0, scx, scy, scum, sn, sbase);

  int bm = blockIdx.x;
  {
    const float* al = w_align + (size_t)bm*NA;
    int pbase = scum[bm*3], pm1 = scum[bm*3+1], pm2 = scum[bm*3+2], pend = scum[bm*3+3];

    float v[KTOP]; int ix[KTOP];
#pragma unroll
    for (int j = 0; j < KTOP; j++){ v[j] = -1.f; ix[j] = 0x7fffffff; }
    for (int p = pbase + tid; p < pend; p += 256){
      int r = bm*3 + ((p >= pm1) + (p >= pm2));
      int idx = p - scum[r];
      int cx = scx[r];
      int yi = idx / cx;
      int xi = idx - yi*cx;
      int a = sbase[r] + (sy0[r] + yi)*sn[r] + (sx0[r] + xi);
      float x = al[a];
      if (x > v[KTOP-1]){
        v[KTOP-1] = x; ix[KTOP-1] = a;
#pragma unroll
        for (int j = KTOP-1; j > 0; j--){
          if (v[j] > v[j-1]){
            float tv = v[j-1]; v[j-1] = v[j]; v[j] = tv;
            int   ti = ix[j-1]; ix[j-1] = ix[j]; ix[j] = ti;
          }
        }
      }
    }
#pragma unroll
    for (int j = 0; j < KTOP; j++){ sv[tid*KTOP+j] = v[j]; si[tid*KTOP+j] = ix[j]; }

    int head = 0;
    for (int r = 0; r < KTOP; r++){
      float cv = sv[tid*KTOP + head];
      int   ci = si[tid*KTOP + head];
      float rv = cv; int ri = ci;
      for (int off = 32; off > 0; off >>= 1){
        float ov = __shfl_down(rv, off);
        int   oi = __shfl_down(ri, off);
        if (ov > rv || (ov == rv && oi < ri)){ rv = ov; ri = oi; }
      }
      if (lane == 0){ wv4[wave] = rv; wi4[wave] = ri; }
      __syncthreads();
      float Wv = wv4[0]; int Wi = wi4[0];
#pragma unroll
      for (int w = 1; w < 4; w++){
        float ov = wv4[w]; int oi = wi4[w];
        if (ov > Wv || (ov == Wv && oi < Wi)){ Wv = ov; Wi = oi; }
      }
      if (ci == Wi && head < KTOP-1) head++;
      if (tid == 0)
        __hip_atomic_store(&w_sel[bm*KTOP + r], (Wv > 0.f) ? Wi : -1,
                           __ATOMIC_RELAXED, __HIP_MEMORY_SCOPE_AGENT);
      __syncthreads();
    }
  }

  if (tid == 0){
    __threadfence();
    int old = __hip_atomic_fetch_add(done, 1, __ATOMIC_ACQ_REL, __HIP_MEMORY_SCOPE_AGENT);
    sLast = (old == BS*NM - 1) ? 1 : 0;
  }
  __syncthreads();
  if (!sLast) return;

  for (int s = tid; s < BS*NM*KTOP; s += 256)
    sel[s] = __hip_atomic_load(&w_sel[s], __ATOMIC_RELAXED, __HIP_MEMORY_SCOPE_AGENT);
  if (tid < BS*NM){ paB[tid] = 0u; poB[tid] = 0u; }
  if (tid == 0) fcnt = 0;
  __syncthreads();

  for (int s = tid; s < BS*NM*KTOP; s += 256){
    int a = sel[s];
    if (a >= 0){
      int sbm = s / KTOP;
      int b   = sbm / NM;
      int s0 = b*NM*KTOP;
      int cnt = 0, minS = 1 << 30;
      for (int s2 = s0; s2 < s0 + NM*KTOP; s2++){
        if (sel[s2] == a){ cnt++; if (s2 < minS) minS = s2; }
      }
      if (s == minS){
        int bi = sbm - b*NM;
        if (cnt > 1){
          float bv = -1.f; bi = 0;
#pragma unroll
          for (int mm = 0; mm < NM; mm++){
            float vv = w_ovl[((size_t)(b*NM+mm))*NA + a];
            if (vv > bv){ bv = vv; bi = mm; }
          }
        }
        int bmw = b*NM + bi;
        int ta  = b*NA + a;
        o_maskpos[(size_t)bmw*NA + a] = 1.f;
        o_gtidx[ta] = (float)bi;
        o_fg[ta] = 1.f;
        int lbl = gl[bmw]; if (lbl < 0) lbl = 0;
        o_labels[ta] = (float)lbl;
        const float* bx = gtb + bmw*4;
        ((float4*)o_bboxes)[ta] = make_float4(bx[0], bx[1], bx[2], bx[3]);
        float av  = w_align[(size_t)bmw*NA + a];
        float ovv = w_ovl[(size_t)bmw*NA + a];
        atomicMax(&paB[bmw], __float_as_uint(av));
        atomicMax(&poB[bmw], __float_as_uint(ovv));
        int j = atomicAdd(&fcnt, 1);
        fT[j] = bmw*NA + a; fA[j] = ta; fL[j] = lbl; fV[j] = av;
      }
    }
  }
  __syncthreads();

  int nf = fcnt;
  for (int j = tid; j < nf; j += 256){
    int tf = fT[j];
    int a = tf % NA; int bmw = tf / NA;
    int lv = (a < 6400) ? 0 : ((a < 8000) ? 1 : 2);
    int ai = a - ((lv == 0) ? 0 : ((lv == 1) ? 6400 : 8000));
    int r = bmw*3 + lv;
    int n = sn[r];
    int y = ai / n, x = ai - y*n;
    int p = scum[r] + (y - sy0[r])*scx[r] + (x - sx0[r]);
    const float4* src = (const float4*)(w_dist + (size_t)p*NBIN);
    float4* dst = (float4*)(o_gtdist + (size_t)tf*NBIN);
    float vmin = 1e30f, vmax = 0.f;
#pragma unroll
    for (int q = 0; q < 9; q++){
      float4 v4 = src[q];
      dst[q] = v4;
      vmin = fminf(vmin, fminf(fminf(v4.x, v4.y), fminf(v4.z, v4.w)));
      vmax = fmaxf(vmax, fmaxf(fmaxf(v4.x, v4.y), fmaxf(v4.z, v4.w)));
    }
    o_cent[tf] = sqrtf(vmin / vmax);
    float paf = __uint_as_float(paB[bmw]);
    float pof = __uint_as_float(poB[bmw]);
    o_scores[(size_t)fA[j]*NC + fL[j]] = fV[j] * pof / (paf + 1e-9f);
  }
}

extern "C" void kernel_launch(void* const* d_in, const int* in_sizes, int n_in,
                              void* d_out, int out_size, void* d_ws, size_t ws_size,
                              hipStream_t stream){
  const float* pds  = (const float*)d_in[0]; // (2,8400,80)
  const float* pdb  = (const float*)d_in[1]; // (2,8400,36)
  const float* anc  = (const float*)d_in[2]; // (8400,2)
  const int*   gl   = (const int*)  d_in[3]; // (2,10,1)
  const float* gtb  = (const float*)d_in[4]; // (2,10,4)
  const float* mgt  = (const float*)d_in[5]; // (2,10,1)
  const float* coor = (const float*)d_in[6]; // (2,10,720)

  float* out = (float*)d_out;
  float* o_labels  = out;                                 // 16800
  float* o_bboxes  = o_labels + BS*NA;                    // 67200
  float* o_scores  = o_bboxes + BS*NA*4;                  // 1344000
  float* o_maskpos = o_scores + (size_t)BS*NA*NC;         // 168000
  float* o_gtidx   = o_maskpos + BS*NM*NA;                // 16800
  float* o_gtdist  = o_gtidx + BS*NA;                     // 6048000
  float* o_cent    = o_gtdist + (size_t)BS*NM*NA*NBIN;    // 168000
  float* o_fg      = o_cent + BS*NM*NA;                   // 16800

  float* wf      = (float*)d_ws;
  int*   done    = (int*)d_ws;                            // wf[0], zeroed by k_dist
  float* w_align = wf + 16;
  float* w_ovl   = w_align + BS*NM*NA;
  float* w_dist  = w_ovl + BS*NM*NA;                      // WDIST_CAP*36 floats
  int*   w_sel   = (int*)(w_dist + (size_t)WDIST_CAP*NBIN);

  k_dist<<<2048, 256, 0, stream>>>(pds, pdb, anc, gl, gtb, mgt, coor, out, wf);
  k_tail<<<BS*NM, 256, 0, stream>>>(gtb, mgt, w_align, w_ovl, w_dist, gl,
                                    o_labels, o_bboxes, o_maskpos, o_gtidx, o_fg,
                                    o_gtdist, o_cent, o_scores, w_sel, done);
}